// Round 1
// baseline (71.939 us; speedup 1.0000x reference)
//
#include <hip/hip_runtime.h>
#include <hip/hip_bf16.h>

typedef __attribute__((ext_vector_type(8))) short bf16x8;
typedef __attribute__((ext_vector_type(4))) float f32x4;

__device__ __forceinline__ ushort f2bf(float f) {
    union { float f; unsigned u; } v; v.f = f;
    unsigned u = v.u;
    unsigned r = (u + 0x7FFFu + ((u >> 16) & 1u)) >> 16;   // RNE
    return (ushort)r;
}

// ---------- prep: WhT[n][k] = bf16(Wh[k][n]) ----------
__global__ void prep_whT(const float* __restrict__ Wh, ushort* __restrict__ whT) {
    int n = blockIdx.x;   // 0..255
    int k = threadIdx.x;  // 0..255
    whT[n * 256 + k] = f2bf(Wh[k * 256 + n]);
}

// ---------- main: out = gamma*(x@Wh + bh) + x ----------
// block: 256 thr (4 waves), tile 64 rows x 256 cols, K=256
__global__ __launch_bounds__(256, 2) void ccsa_gemm(
    const float* __restrict__ x, const ushort* __restrict__ whT,
    const float* __restrict__ bh, const float* __restrict__ gamma,
    float* __restrict__ out)
{
    extern __shared__ char lds[];            // [0,32768): A 64x256 bf16 swz
                                             // [32768,65536): B chunk 256n x 64k bf16 swz
    const int tid  = threadIdx.x;
    const int lane = tid & 63;
    const int wv   = tid >> 6;
    const int r15  = lane & 15;
    const int g    = lane >> 4;
    const int swz  = (r15 & 7) << 4;

    const long row0 = (long)blockIdx.x * 64;
    const float* xblk = x + row0 * 256;

    // ---- stage A: 64x256 fp32 -> bf16, swizzled ----
#pragma unroll
    for (int p = 0; p < 8; ++p) {
        int lin = p * 2048 + tid * 8;
        int r = lin >> 8;
        int c = lin & 255;
        float4 a0 = *(const float4*)(xblk + lin);
        float4 a1 = *(const float4*)(xblk + lin + 4);
        uint4 pk;
        pk.x = (unsigned)f2bf(a0.x) | ((unsigned)f2bf(a0.y) << 16);
        pk.y = (unsigned)f2bf(a0.z) | ((unsigned)f2bf(a0.w) << 16);
        pk.z = (unsigned)f2bf(a1.x) | ((unsigned)f2bf(a1.y) << 16);
        pk.w = (unsigned)f2bf(a1.z) | ((unsigned)f2bf(a1.w) << 16);
        int addr = r * 512 + ((c * 2) ^ ((r & 7) << 4));
        *(uint4*)(lds + addr) = pk;
    }

    // ---- B chunk staging: WhT[n][kc*64 .. +64) -> lds swizzled ----
    auto stage_b = [&](int kc) {
#pragma unroll
        for (int i = 0; i < 8; ++i) {
            int piece = i * 256 + tid;       // 0..2047
            int n  = piece >> 3;
            int ks = piece & 7;              // 16B slot along k
            uint4 v = *(const uint4*)(whT + n * 256 + kc * 64 + ks * 8);
            int addr = 32768 + n * 128 + ((ks * 16) ^ ((n & 7) << 4));
            *(uint4*)(lds + addr) = v;
        }
    };

    f32x4 acc[4][4] = {};

    stage_b(0);
    __syncthreads();

    const int koff0 = (16 * g) ^ swz;        // ksl = 0
    const int koff1 = (64 + 16 * g) ^ swz;   // ksl = 1

    for (int kc = 0; kc < 4; ++kc) {
#pragma unroll
        for (int ksl = 0; ksl < 2; ++ksl) {
            const int ko = ksl ? koff1 : koff0;
            bf16x8 af[4], bfr[4];
#pragma unroll
            for (int mi = 0; mi < 4; ++mi)
                af[mi] = *(const bf16x8*)(lds + mi * 8192 + r15 * 512 + kc * 128 + ko);
#pragma unroll
            for (int ni = 0; ni < 4; ++ni)
                bfr[ni] = *(const bf16x8*)(lds + 32768 + wv * 8192 + ni * 2048 + r15 * 128 + ko);
#pragma unroll
            for (int mi = 0; mi < 4; ++mi)
#pragma unroll
                for (int ni = 0; ni < 4; ++ni)
                    acc[mi][ni] = __builtin_amdgcn_mfma_f32_16x16x32_bf16(
                        af[mi], bfr[ni], acc[mi][ni], 0, 0, 0);
        }
        if (kc < 3) {
            __syncthreads();
            stage_b(kc + 1);
            __syncthreads();
        }
    }

    // ---- epilogue: out = gm*(acc + bh) + x  (x from bf16 A tile) ----
    const float gm = gamma[0];
    float bias[4];
#pragma unroll
    for (int ni = 0; ni < 4; ++ni) bias[ni] = bh[wv * 64 + ni * 16 + r15];

#pragma unroll
    for (int mi = 0; mi < 4; ++mi) {
#pragma unroll
        for (int rr = 0; rr < 4; ++rr) {
            int row = mi * 16 + g * 4 + rr;
#pragma unroll
            for (int ni = 0; ni < 4; ++ni) {
                int col2 = wv * 128 + ni * 32 + r15 * 2;
                int addr = row * 512 + (col2 ^ ((row & 7) << 4));
                ushort xv = *(const ushort*)(lds + addr);
                float xf = __uint_as_float(((unsigned)xv) << 16);
                float val = gm * (acc[mi][ni][rr] + bias[ni]) + xf;
                out[(row0 + row) * 256 + wv * 64 + ni * 16 + r15] = val;
            }
        }
    }
}

extern "C" void kernel_launch(void* const* d_in, const int* in_sizes, int n_in,
                              void* d_out, int out_size, void* d_ws, size_t ws_size,
                              hipStream_t stream) {
    const float* x  = (const float*)d_in[0];
    const float* Wh = (const float*)d_in[5];
    const float* bh = (const float*)d_in[6];
    const float* gm = (const float*)d_in[7];
    float* out = (float*)d_out;
    ushort* whT = (ushort*)d_ws;   // 128 KB scratch

    prep_whT<<<256, 256, 0, stream>>>(Wh, whT);
    ccsa_gemm<<<2048, 256, 65536, stream>>>(x, whT, bh, gm, out);
}

// Round 2
// 70.698 us; speedup vs baseline: 1.0175x; 1.0175x over previous
//
#include <hip/hip_runtime.h>
#include <hip/hip_bf16.h>

typedef __attribute__((ext_vector_type(8))) short bf16x8;
typedef __attribute__((ext_vector_type(4))) float f32x4;

__device__ __forceinline__ unsigned f2bf(float f) {
    union { float f; unsigned u; } v; v.f = f;
    unsigned u = v.u;
    return (u + 0x7FFFu + ((u >> 16) & 1u)) >> 16;   // RNE
}

// ---------- prep: WhT[n][k] = bf16(Wh[k][n]) ----------
__global__ void prep_whT(const float* __restrict__ Wh, ushort* __restrict__ whT) {
    int n = blockIdx.x;   // 0..255
    int k = threadIdx.x;  // 0..255
    whT[n * 256 + k] = (ushort)f2bf(Wh[k * 256 + n]);
}

// ---------- main: out = gamma*(x@Wh + bh) + x ----------
// block: 256 thr (4 waves), tile 64 rows x 256 cols, K=256
// A (x tile) in 32KB LDS (bf16, XOR-swizzled); B (whT) read directly from
// global (L2-resident, shared by all blocks) -> barrier-free K-loop.
__global__ __launch_bounds__(256, 4) void ccsa_gemm(
    const float* __restrict__ x, const ushort* __restrict__ whT,
    const float* __restrict__ bh, const float* __restrict__ gamma,
    float* __restrict__ out)
{
    __shared__ char lds[32768];              // A 64x256 bf16, swizzled
    const int tid  = threadIdx.x;
    const int lane = tid & 63;
    const int wv   = tid >> 6;
    const int r15  = lane & 15;
    const int g    = lane >> 4;
    const int swz  = (r15 & 7) << 4;

    const long row0 = (long)blockIdx.x * 64;
    const float* xblk = x + row0 * 256;

    // ---- stage A: 64x256 fp32 -> bf16, swizzled ----
#pragma unroll
    for (int p = 0; p < 8; ++p) {
        int lin = p * 2048 + tid * 8;
        int r = lin >> 8;
        int c = lin & 255;
        float4 a0 = *(const float4*)(xblk + lin);
        float4 a1 = *(const float4*)(xblk + lin + 4);
        uint4 pk;
        pk.x = f2bf(a0.x) | (f2bf(a0.y) << 16);
        pk.y = f2bf(a0.z) | (f2bf(a0.w) << 16);
        pk.z = f2bf(a1.x) | (f2bf(a1.y) << 16);
        pk.w = f2bf(a1.z) | (f2bf(a1.w) << 16);
        int addr = r * 512 + ((c * 2) ^ ((r & 7) << 4));
        *(uint4*)(lds + addr) = pk;
    }

    // B fragment base pointers: n = wv*64 + ni*16 + r15, k-offset g*8
    const ushort* bp0 = whT + (wv * 64 +  0 + r15) * 256 + g * 8;
    const ushort* bp1 = whT + (wv * 64 + 16 + r15) * 256 + g * 8;
    const ushort* bp2 = whT + (wv * 64 + 32 + r15) * 256 + g * 8;
    const ushort* bp3 = whT + (wv * 64 + 48 + r15) * 256 + g * 8;

    __syncthreads();

    f32x4 acc[4][4] = {};

#pragma unroll
    for (int ksl = 0; ksl < 8; ++ksl) {
        bf16x8 bc[4];
        bc[0] = *(const bf16x8*)(bp0 + ksl * 32);
        bc[1] = *(const bf16x8*)(bp1 + ksl * 32);
        bc[2] = *(const bf16x8*)(bp2 + ksl * 32);
        bc[3] = *(const bf16x8*)(bp3 + ksl * 32);

        const int ko = (ksl * 64 + g * 16) ^ swz;
        bf16x8 af[4];
#pragma unroll
        for (int mi = 0; mi < 4; ++mi)
            af[mi] = *(const bf16x8*)(lds + (mi * 16 + r15) * 512 + ko);

#pragma unroll
        for (int mi = 0; mi < 4; ++mi)
#pragma unroll
            for (int ni = 0; ni < 4; ++ni)
                acc[mi][ni] = __builtin_amdgcn_mfma_f32_16x16x32_bf16(
                    af[mi], bc[ni], acc[mi][ni], 0, 0, 0);
    }

    // ---- epilogue: out = gm*(acc + bh) + x  (x residual from bf16 A tile) ----
    const float gm = gamma[0];
    float bias[4];
#pragma unroll
    for (int ni = 0; ni < 4; ++ni) bias[ni] = bh[wv * 64 + ni * 16 + r15];

#pragma unroll
    for (int mi = 0; mi < 4; ++mi) {
#pragma unroll
        for (int rr = 0; rr < 4; ++rr) {
            int row = mi * 16 + g * 4 + rr;
#pragma unroll
            for (int ni = 0; ni < 4; ++ni) {
                int col2 = wv * 128 + ni * 32 + r15 * 2;
                int addr = row * 512 + (col2 ^ ((row & 7) << 4));
                ushort xv = *(const ushort*)(lds + addr);
                float xf = __uint_as_float(((unsigned)xv) << 16);
                float val = gm * (acc[mi][ni][rr] + bias[ni]) + xf;
                out[(row0 + row) * 256 + wv * 64 + ni * 16 + r15] = val;
            }
        }
    }
}

extern "C" void kernel_launch(void* const* d_in, const int* in_sizes, int n_in,
                              void* d_out, int out_size, void* d_ws, size_t ws_size,
                              hipStream_t stream) {
    const float* x  = (const float*)d_in[0];
    const float* Wh = (const float*)d_in[5];
    const float* bh = (const float*)d_in[6];
    const float* gm = (const float*)d_in[7];
    float* out = (float*)d_out;
    ushort* whT = (ushort*)d_ws;   // 128 KB scratch

    prep_whT<<<256, 256, 0, stream>>>(Wh, whT);
    ccsa_gemm<<<2048, 256, 0, stream>>>(x, whT, bh, gm, out);
}